// Round 3
// baseline (410.225 us; speedup 1.0000x reference)
//
#include <hip/hip_runtime.h>
#include <hip/hip_bf16.h>

#define B_DIM 4
#define C_DIM 192
#define T_SEQ 2048
#define H_DIM 2
#define K_DIM 96
#define BAND 256
#define IT 16
#define WMAX (2*BAND + IT)   // 528
#define BLK2 256
#define VCH_ROWS 32
#define VCH_STRIDE 100       // floats: 400B row pitch, 16B-aligned for float4 reads

#define NQ_ELEMS  ((size_t)B_DIM*H_DIM*T_SEQ*K_DIM)   // 1,572,864 floats

// ---------------------------------------------------------------------------
// Kernel 1: q/k/v projections (all fp32).
// q[b,h,t,k] = (x[b,:,t]·Wq[:,hK+k] + bq)/sqrt(K); k,v likewise from c.
// Block: 192 threads = one output channel each; handles 8 consecutive t.
// ---------------------------------------------------------------------------
__global__ __launch_bounds__(192)
void proj_kernel(const float* __restrict__ x, const float* __restrict__ cin,
                 const float* __restrict__ Wq, const float* __restrict__ bq,
                 const float* __restrict__ Wk, const float* __restrict__ bk,
                 const float* __restrict__ Wv, const float* __restrict__ bv,
                 float* __restrict__ ws)
{
    __shared__ float xs2[8*C_DIM];   // [tt][c] layout
    __shared__ float cs2[8*C_DIM];
    const int b   = blockIdx.x / (T_SEQ/8);
    const int t0  = (blockIdx.x % (T_SEQ/8)) * 8;
    const int tid = threadIdx.x;

    {
        const size_t coloff = (size_t)(b*C_DIM + tid)*T_SEQ + t0;
        union { float4 f4[2]; float f[8]; } xu, cu;
        xu.f4[0] = *reinterpret_cast<const float4*>(x + coloff);
        xu.f4[1] = *reinterpret_cast<const float4*>(x + coloff + 4);
        cu.f4[0] = *reinterpret_cast<const float4*>(cin + coloff);
        cu.f4[1] = *reinterpret_cast<const float4*>(cin + coloff + 4);
        #pragma unroll
        for (int tt = 0; tt < 8; ++tt) {
            xs2[tt*C_DIM + tid] = xu.f[tt];
            cs2[tt*C_DIM + tid] = cu.f[tt];
        }
    }
    __syncthreads();

    const int d = tid;
    float accq[8], acck[8], accv[8];
    const float bqv = bq[d], bkv = bk[d], bvv = bv[d];
    #pragma unroll
    for (int tt = 0; tt < 8; ++tt) { accq[tt] = bqv; acck[tt] = bkv; accv[tt] = bvv; }

    for (int c4 = 0; c4 < C_DIM/4; ++c4) {
        float wq[4], wk[4], wv[4];
        #pragma unroll
        for (int u = 0; u < 4; ++u) {
            const int ci = c4*4 + u;
            wq[u] = Wq[ci*C_DIM + d];
            wk[u] = Wk[ci*C_DIM + d];
            wv[u] = Wv[ci*C_DIM + d];
        }
        #pragma unroll
        for (int tt = 0; tt < 8; ++tt) {
            const float4 xv = *reinterpret_cast<const float4*>(xs2 + tt*C_DIM + c4*4);
            const float4 cv = *reinterpret_cast<const float4*>(cs2 + tt*C_DIM + c4*4);
            accq[tt] = fmaf(xv.x, wq[0], fmaf(xv.y, wq[1], fmaf(xv.z, wq[2], fmaf(xv.w, wq[3], accq[tt]))));
            acck[tt] = fmaf(cv.x, wk[0], fmaf(cv.y, wk[1], fmaf(cv.z, wk[2], fmaf(cv.w, wk[3], acck[tt]))));
            accv[tt] = fmaf(cv.x, wv[0], fmaf(cv.y, wv[1], fmaf(cv.z, wv[2], fmaf(cv.w, wv[3], accv[tt]))));
        }
    }

    const float qscale = 0.10206207261596577f;  // 1/sqrt(96)
    const int h = d / K_DIM, kk = d % K_DIM;
    float* qws = ws;
    float* kws = ws + NQ_ELEMS;
    float* vws = ws + 2*NQ_ELEMS;
    const size_t base = ((size_t)((b*H_DIM + h)*T_SEQ + t0))*K_DIM + kk;
    #pragma unroll
    for (int tt = 0; tt < 8; ++tt) {
        qws[base + (size_t)tt*K_DIM] = accq[tt] * qscale;   // pre-scaled q
        kws[base + (size_t)tt*K_DIM] = acck[tt];
        vws[base + (size_t)tt*K_DIM] = accv[tt];
    }
}

// ---------------------------------------------------------------------------
// Kernel 2: banded attention. Block = (b,h, 16 query rows). Window <= 528.
// Band |i-j|<=256 is exact: ref gives invalid entries score -1e4, whose
// exp(-1e4 - m) underflows to 0 in fp32 -> identical to our -inf.
// ---------------------------------------------------------------------------
__global__ __launch_bounds__(BLK2)
void attn_kernel(const float* __restrict__ relk, const float* __restrict__ relv,
                 const int* __restrict__ mask, float* __restrict__ ws)
{
    __shared__ float qtile[IT*K_DIM];            // 6 KB
    __shared__ float rl[IT*9];                   // rel-k logits per (row, offset)
    __shared__ float p[IT*WMAX];                 // 33 KB scores -> probabilities
    __shared__ float vch[VCH_ROWS*VCH_STRIDE];   // 12.5 KB staged V chunk

    const float* qws = ws;
    const float* kws = ws + NQ_ELEMS;
    const float* vws = ws + 2*NQ_ELEMS;
    float* obtc      = ws + 3*NQ_ELEMS;

    const int bh  = blockIdx.x / (T_SEQ/IT);
    const int i0  = (blockIdx.x % (T_SEQ/IT)) * IT;
    const int b   = bh / H_DIM;
    const int h   = bh % H_DIM;
    const int tid = threadIdx.x;

    const size_t qkv_base = (size_t)bh * T_SEQ * K_DIM;

    for (int idx = tid; idx < IT*K_DIM; idx += BLK2)
        qtile[idx] = qws[qkv_base + (size_t)i0*K_DIM + idx];
    __syncthreads();

    if (tid < IT*9) {                            // rel-k logits: qs_i · emb_rel_k[dd]
        const int r = tid/9, dd = tid%9;
        float s = 0.f;
        for (int k = 0; k < K_DIM; ++k)
            s += qtile[r*K_DIM + k] * relk[dd*K_DIM + k];
        rl[tid] = s;
    }

    const int jlo  = max(0, i0 - BAND);
    const int jhi  = min(T_SEQ - 1, i0 + IT - 1 + BAND);
    const int wlen = jhi - jlo + 1;
    __syncthreads();

    // ---- scores: each thread owns 2 key columns; k-rows read once per block
    for (int base = 0; base < wlen; base += 2*BLK2) {
        const int jj1 = base + tid;
        if (jj1 >= wlen) break;
        const int jj2 = jj1 + BLK2;
        const bool v2 = (jj2 < wlen);
        const float4* k1 = reinterpret_cast<const float4*>(kws + qkv_base + (size_t)(jlo + jj1)*K_DIM);
        const float4* k2 = v2 ? reinterpret_cast<const float4*>(kws + qkv_base + (size_t)(jlo + jj2)*K_DIM) : k1;
        float acc1[IT], acc2[IT];
        #pragma unroll
        for (int r = 0; r < IT; ++r) { acc1[r] = 0.f; acc2[r] = 0.f; }
        for (int k4 = 0; k4 < K_DIM/4; ++k4) {
            const float4 kv1 = k1[k4];
            const float4 kv2 = k2[k4];
            #pragma unroll
            for (int r = 0; r < IT; ++r) {
                const float4 qv = *reinterpret_cast<const float4*>(qtile + r*K_DIM + k4*4);
                acc1[r] += qv.x*kv1.x + qv.y*kv1.y + qv.z*kv1.z + qv.w*kv1.w;
                acc2[r] += qv.x*kv2.x + qv.y*kv2.y + qv.z*kv2.z + qv.w*kv2.w;
            }
        }
        #pragma unroll
        for (int r = 0; r < IT; ++r) {
            const int i = i0 + r;
            {
                const int j  = jlo + jj1;
                const int dd = j - i;
                const int ad = dd < 0 ? -dd : dd;
                float s = -INFINITY;
                if (ad <= BAND && mask[((size_t)b*T_SEQ + i)*T_SEQ + j] != 0) {
                    s = acc1[r];
                    if (ad <= 4) s += rl[r*9 + dd + 4];
                    s -= log1pf((float)ad);
                }
                p[r*WMAX + jj1] = s;
            }
            if (v2) {
                const int j  = jlo + jj2;
                const int dd = j - i;
                const int ad = dd < 0 ? -dd : dd;
                float s = -INFINITY;
                if (ad <= BAND && mask[((size_t)b*T_SEQ + i)*T_SEQ + j] != 0) {
                    s = acc2[r];
                    if (ad <= 4) s += rl[r*9 + dd + 4];
                    s -= log1pf((float)ad);
                }
                p[r*WMAX + jj2] = s;
            }
        }
    }
    __syncthreads();

    // ---- softmax: one wave per 4 rows, shuffle reductions over 64 lanes
    {
        const int wave = tid >> 6, lane = tid & 63;
        for (int r = wave*4; r < wave*4 + 4; ++r) {
            float m = -INFINITY;
            for (int jj = lane; jj < wlen; jj += 64) m = fmaxf(m, p[r*WMAX + jj]);
            #pragma unroll
            for (int off = 32; off > 0; off >>= 1) m = fmaxf(m, __shfl_xor(m, off, 64));
            float ssum = 0.f;
            for (int jj = lane; jj < wlen; jj += 64) {
                const float e = __expf(p[r*WMAX + jj] - m);
                p[r*WMAX + jj] = e;
                ssum += e;
            }
            #pragma unroll
            for (int off = 32; off > 0; off >>= 1) ssum += __shfl_xor(ssum, off, 64);
            const float inv = 1.0f / ssum;
            for (int jj = lane; jj < wlen; jj += 64) p[r*WMAX + jj] *= inv;
        }
    }
    __syncthreads();

    // ---- P·V with LDS-staged V chunks; 16 rows x 24 float4 outputs
    float4 oacc[2];
    oacc[0] = make_float4(0.f,0.f,0.f,0.f);
    oacc[1] = make_float4(0.f,0.f,0.f,0.f);
    const int nch = (wlen + VCH_ROWS - 1)/VCH_ROWS;
    for (int chi = 0; chi < nch; ++chi) {
        const int j0 = chi*VCH_ROWS;
        const int nj = min(VCH_ROWS, wlen - j0);
        __syncthreads();
        for (int idx = tid; idx < nj*K_DIM; idx += BLK2) {
            const int jj = idx / K_DIM, kk = idx % K_DIM;
            vch[jj*VCH_STRIDE + kk] = vws[qkv_base + (size_t)(jlo + j0 + jj)*K_DIM + kk];
        }
        __syncthreads();
        #pragma unroll
        for (int u = 0; u < 2; ++u) {
            const int idx = tid + u*BLK2;
            if (idx < IT*(K_DIM/4)) {
                const int r = idx / (K_DIM/4), kq = idx % (K_DIM/4);
                float4 a = oacc[u];
                for (int jj = 0; jj < nj; ++jj) {
                    const float pv = p[r*WMAX + j0 + jj];
                    const float4 vv = *reinterpret_cast<const float4*>(vch + jj*VCH_STRIDE + kq*4);
                    a.x = fmaf(pv, vv.x, a.x);
                    a.y = fmaf(pv, vv.y, a.y);
                    a.z = fmaf(pv, vv.z, a.z);
                    a.w = fmaf(pv, vv.w, a.w);
                }
                oacc[u] = a;
            }
        }
    }

    // ---- rel_v epilogue + store [B,T,C]
    #pragma unroll
    for (int u = 0; u < 2; ++u) {
        const int idx = tid + u*BLK2;
        if (idx < IT*(K_DIM/4)) {
            const int r = idx / (K_DIM/4), kq = idx % (K_DIM/4);
            const int i = i0 + r;
            float4 a = oacc[u];
            #pragma unroll
            for (int dd = 0; dd < 9; ++dd) {
                const int j = i + dd - 4;
                if (j >= 0 && j < T_SEQ) {
                    const float pv = p[r*WMAX + (j - jlo)];
                    a.x = fmaf(pv, relv[dd*K_DIM + kq*4 + 0], a.x);
                    a.y = fmaf(pv, relv[dd*K_DIM + kq*4 + 1], a.y);
                    a.z = fmaf(pv, relv[dd*K_DIM + kq*4 + 2], a.z);
                    a.w = fmaf(pv, relv[dd*K_DIM + kq*4 + 3], a.w);
                }
            }
            float* op = obtc + ((size_t)(b*T_SEQ + i))*C_DIM + h*K_DIM + kq*4;
            *reinterpret_cast<float4*>(op) = a;
        }
    }
}

// ---------------------------------------------------------------------------
// Kernel 3: output projection -> fp32 y[B,C,T]
// ---------------------------------------------------------------------------
__global__ __launch_bounds__(192)
void oproj_kernel(const float* __restrict__ Wo, const float* __restrict__ bo,
                  float* __restrict__ y, const float* __restrict__ ws)
{
    __shared__ float xs2[8*C_DIM];
    const float* obtc = ws + 3*NQ_ELEMS;
    const int b   = blockIdx.x / (T_SEQ/8);
    const int t0  = (blockIdx.x % (T_SEQ/8)) * 8;
    const int tid = threadIdx.x;   // output channel o

    #pragma unroll
    for (int tt = 0; tt < 8; ++tt)
        xs2[tt*C_DIM + tid] = obtc[((size_t)(b*T_SEQ + t0 + tt))*C_DIM + tid];
    __syncthreads();

    float acc[8];
    const float bov = bo[tid];
    #pragma unroll
    for (int tt = 0; tt < 8; ++tt) acc[tt] = bov;

    for (int d4 = 0; d4 < C_DIM/4; ++d4) {
        float w[4];
        #pragma unroll
        for (int u = 0; u < 4; ++u) w[u] = Wo[(d4*4 + u)*C_DIM + tid];
        #pragma unroll
        for (int tt = 0; tt < 8; ++tt) {
            const float4 xv = *reinterpret_cast<const float4*>(xs2 + tt*C_DIM + d4*4);
            acc[tt] = fmaf(xv.x, w[0], fmaf(xv.y, w[1], fmaf(xv.z, w[2], fmaf(xv.w, w[3], acc[tt]))));
        }
    }

    float* yp = y + ((size_t)(b*C_DIM + tid))*T_SEQ + t0;
    union { float4 f4[2]; float f[8]; } ou;
    #pragma unroll
    for (int tt = 0; tt < 8; ++tt) ou.f[tt] = acc[tt];
    *reinterpret_cast<float4*>(yp)     = ou.f4[0];
    *reinterpret_cast<float4*>(yp + 4) = ou.f4[1];
}

// ---------------------------------------------------------------------------
extern "C" void kernel_launch(void* const* d_in, const int* in_sizes, int n_in,
                              void* d_out, int out_size, void* d_ws, size_t ws_size,
                              hipStream_t stream)
{
    const float* x    = (const float*)d_in[0];
    const float* c    = (const float*)d_in[1];
    const float* Wq   = (const float*)d_in[2];
    const float* bq   = (const float*)d_in[3];
    const float* Wk   = (const float*)d_in[4];
    const float* bk   = (const float*)d_in[5];
    const float* Wv   = (const float*)d_in[6];
    const float* bv   = (const float*)d_in[7];
    const float* Wo   = (const float*)d_in[8];
    const float* bo   = (const float*)d_in[9];
    const float* relk = (const float*)d_in[10];
    const float* relv = (const float*)d_in[11];
    const int*   mask = (const int*)d_in[12];
    float*       y    = (float*)d_out;
    float*       ws   = (float*)d_ws;   // qws | kws | vws | obtc  (4 x 1.57M fp32)

    hipLaunchKernelGGL(proj_kernel, dim3(B_DIM*(T_SEQ/8)), dim3(192), 0, stream,
                       x, c, Wq, bq, Wk, bk, Wv, bv, ws);
    hipLaunchKernelGGL(attn_kernel, dim3(B_DIM*H_DIM*(T_SEQ/IT)), dim3(BLK2), 0, stream,
                       relk, relv, mask, ws);
    hipLaunchKernelGGL(oproj_kernel, dim3(B_DIM*(T_SEQ/8)), dim3(192), 0, stream,
                       Wo, bo, y, ws);
}

// Round 4
// 276.892 us; speedup vs baseline: 1.4815x; 1.4815x over previous
//
#include <hip/hip_runtime.h>
#include <hip/hip_bf16.h>

#define B_DIM 4
#define C_DIM 192
#define T_SEQ 2048
#define H_DIM 2
#define K_DIM 96
#define BAND 256
#define IT 16            // q rows per attn block
#define WSLOT 544        // padded window slots (wlen <= 528)
#define W_P 548          // p LDS row stride (dwords): 548%32=4 -> 2-way banks, 16B aligned
#define PO_S 105         // partial-O row stride

typedef __attribute__((ext_vector_type(8))) short bf16x8;
typedef __attribute__((ext_vector_type(4))) float f32x4;
#define MFMA16 __builtin_amdgcn_mfma_f32_16x16x32_bf16

__device__ __forceinline__ float bf2f(__hip_bfloat16 v) { return __bfloat162float(v); }
__device__ __forceinline__ short f2bf_bits(float f) {
    union { __hip_bfloat16 h; short s; } u; u.h = __float2bfloat16(f); return u.s;
}

// ---------------------------------------------------------------------------
// Kernel 1: q/k/v projections (fp32 math, bf16 outputs).
// Block: 192 threads (one output channel), 16 consecutive t.
// Outputs: qbf,kbf as [bh][t][96] bf16 (q pre-scaled), vtb as [bh][96][t] bf16.
// ---------------------------------------------------------------------------
__global__ __launch_bounds__(192)
void proj_kernel(const float* __restrict__ x, const float* __restrict__ cin,
                 const float* __restrict__ Wq, const float* __restrict__ bq,
                 const float* __restrict__ Wk, const float* __restrict__ bk,
                 const float* __restrict__ Wv, const float* __restrict__ bv,
                 short* __restrict__ qbf, short* __restrict__ kbf,
                 short* __restrict__ vtb)
{
    __shared__ float xs2[16*C_DIM];   // [tt][c]
    __shared__ float cs2[16*C_DIM];
    const int b   = blockIdx.x / (T_SEQ/16);
    const int t0  = (blockIdx.x % (T_SEQ/16)) * 16;
    const int tid = threadIdx.x;

    {
        const size_t coloff = (size_t)(b*C_DIM + tid)*T_SEQ + t0;
        union { float4 f4[4]; float f[16]; } xu, cu;
        #pragma unroll
        for (int u = 0; u < 4; ++u) {
            xu.f4[u] = *reinterpret_cast<const float4*>(x + coloff + 4*u);
            cu.f4[u] = *reinterpret_cast<const float4*>(cin + coloff + 4*u);
        }
        #pragma unroll
        for (int tt = 0; tt < 16; ++tt) {
            xs2[tt*C_DIM + tid] = xu.f[tt];
            cs2[tt*C_DIM + tid] = cu.f[tt];
        }
    }
    __syncthreads();

    const int d = tid;
    float accq[16], acck[16], accv[16];
    const float bqv = bq[d], bkv = bk[d], bvv = bv[d];
    #pragma unroll
    for (int tt = 0; tt < 16; ++tt) { accq[tt] = bqv; acck[tt] = bkv; accv[tt] = bvv; }

    for (int c4 = 0; c4 < C_DIM/4; ++c4) {
        float wq[4], wk[4], wv[4];
        #pragma unroll
        for (int u = 0; u < 4; ++u) {
            const int ci = c4*4 + u;
            wq[u] = Wq[ci*C_DIM + d];
            wk[u] = Wk[ci*C_DIM + d];
            wv[u] = Wv[ci*C_DIM + d];
        }
        #pragma unroll
        for (int tt = 0; tt < 16; ++tt) {
            const float4 xv = *reinterpret_cast<const float4*>(xs2 + tt*C_DIM + c4*4);
            const float4 cv = *reinterpret_cast<const float4*>(cs2 + tt*C_DIM + c4*4);
            accq[tt] = fmaf(xv.x, wq[0], fmaf(xv.y, wq[1], fmaf(xv.z, wq[2], fmaf(xv.w, wq[3], accq[tt]))));
            acck[tt] = fmaf(cv.x, wk[0], fmaf(cv.y, wk[1], fmaf(cv.z, wk[2], fmaf(cv.w, wk[3], acck[tt]))));
            accv[tt] = fmaf(cv.x, wv[0], fmaf(cv.y, wv[1], fmaf(cv.z, wv[2], fmaf(cv.w, wv[3], accv[tt]))));
        }
    }

    const float qscale = 0.10206207261596577f;  // 1/sqrt(96)
    const int h = d / K_DIM, kk = d % K_DIM;
    const int bh = b*H_DIM + h;
    // q,k row-major [bh][t][96]
    #pragma unroll
    for (int tt = 0; tt < 16; ++tt) {
        const size_t off = ((size_t)bh*T_SEQ + t0 + tt)*K_DIM + kk;
        qbf[off] = f2bf_bits(accq[tt] * qscale);
        kbf[off] = f2bf_bits(acck[tt]);
    }
    // v transposed [bh][k][t], 16 consecutive t -> one 32B store
    {
        union { uint4 u4[2]; short s[16]; } vu;
        #pragma unroll
        for (int tt = 0; tt < 16; ++tt) vu.s[tt] = f2bf_bits(accv[tt]);
        short* vp = vtb + ((size_t)bh*K_DIM + kk)*T_SEQ + t0;
        *reinterpret_cast<uint4*>(vp)     = vu.u4[0];
        *reinterpret_cast<uint4*>(vp + 8) = vu.u4[1];
    }
}

// ---------------------------------------------------------------------------
// Kernel 2: banded MFMA attention. Block = (b,h, 16 q rows), 4 waves.
// Scores: A=Q frags, B=K frags (both direct-from-global, X·Y^T addressing).
// PV: A=P (LDS round trip), B=V^T frags direct-from-global. Waves split k-dim.
// ---------------------------------------------------------------------------
__global__ __launch_bounds__(256)
void attn_kernel(const short* __restrict__ qbf, const short* __restrict__ kbf,
                 const short* __restrict__ vtb,
                 const float* __restrict__ relk, const float* __restrict__ relv,
                 const int* __restrict__ mask, float* __restrict__ obtc)
{
    __shared__ float p_s[IT*W_P];        // 35.1 KB scores -> probabilities
    __shared__ float po[4*IT*PO_S];      // 26.9 KB partial O (one per wave)
    __shared__ float lt[BAND+1];         // log1p table
    __shared__ float rl[IT*9];           // rel-k logits

    const int bh  = blockIdx.x / (T_SEQ/IT);
    const int i0  = (blockIdx.x % (T_SEQ/IT)) * IT;
    const int b   = bh / H_DIM;
    const int h   = bh % H_DIM;
    const int tid = threadIdx.x;
    const int wave = tid >> 6, lane = tid & 63;
    const int q4 = lane >> 4, lr = lane & 15;

    const int jlo  = max(0, i0 - BAND);
    const int jhi  = min(T_SEQ - 1, i0 + IT - 1 + BAND);
    const int wlen = jhi - jlo + 1;

    // ---- init: log1p table + rel-k logits
    for (int idx = tid; idx <= BAND; idx += 256) lt[idx] = log1pf((float)idx);
    if (tid < IT*9) {
        const int r = tid/9, dd = tid%9;
        const short* qrow = qbf + ((size_t)bh*T_SEQ + i0 + r)*K_DIM;
        float s = 0.f;
        for (int k = 0; k < K_DIM; ++k) {
            union { short s; __hip_bfloat16 h; } u; u.s = qrow[k];
            s += bf2f(u.h) * relk[dd*K_DIM + k];
        }
        rl[tid] = s;
    }

    // ---- Q A-frags (per wave, registers): A[m=lane&15][k=q4*8+e]
    bf16x8 qa[3];
    {
        const short* qrow = qbf + ((size_t)bh*T_SEQ + i0 + lr)*K_DIM + q4*8;
        #pragma unroll
        for (int kc = 0; kc < 3; ++kc)
            qa[kc] = *reinterpret_cast<const bf16x8*>(qrow + kc*32);
    }

    // ---- scores: j-tiles of 16, waves interleave; raw S -> p_s (C layout)
    for (int jt = wave; jt < WSLOT/16; jt += 4) {
        int jr = jlo + jt*16 + lr;
        if (jr > T_SEQ-1) jr = T_SEQ-1;          // clamp; junk masked later
        const short* krow = kbf + ((size_t)bh*T_SEQ + jr)*K_DIM + q4*8;
        f32x4 s = {0.f, 0.f, 0.f, 0.f};
        #pragma unroll
        for (int kc = 0; kc < 3; ++kc) {
            const bf16x8 kb = *reinterpret_cast<const bf16x8*>(krow + kc*32);
            s = MFMA16(qa[kc], kb, s, 0, 0, 0);
        }
        #pragma unroll
        for (int e = 0; e < 4; ++e)
            p_s[(q4*4 + e)*W_P + jt*16 + lr] = s[e];
    }
    __syncthreads();

    // ---- postprocess + softmax: row r owned by 16 threads (within one wave)
    {
        const int r = tid >> 4, sj = tid & 15;
        const int i = i0 + r;
        const size_t mrow = ((size_t)b*T_SEQ + i)*T_SEQ;
        float m = -INFINITY;
        for (int j = sj; j < WSLOT; j += 16) {
            float val = -INFINITY;
            if (j < wlen) {
                const int jg = jlo + j;
                const int dd = jg - i;
                const int ad = dd < 0 ? -dd : dd;
                if (ad <= BAND && mask[mrow + jg] != 0) {
                    val = p_s[r*W_P + j] - lt[ad];
                    if ((unsigned)(dd + 4) <= 8u) val += rl[r*9 + dd + 4];
                }
            }
            p_s[r*W_P + j] = val;
            m = fmaxf(m, val);
        }
        #pragma unroll
        for (int off = 8; off > 0; off >>= 1) m = fmaxf(m, __shfl_xor(m, off, 64));
        if (m == -INFINITY) m = 0.f;
        float ssum = 0.f;
        for (int j = sj; j < WSLOT; j += 16) {
            const float e = __expf(p_s[r*W_P + j] - m);
            p_s[r*W_P + j] = e;
            ssum += e;
        }
        #pragma unroll
        for (int off = 8; off > 0; off >>= 1) ssum += __shfl_xor(ssum, off, 64);
        const float inv = ssum > 0.f ? 1.f/ssum : 0.f;
        for (int j = sj; j < WSLOT; j += 16) p_s[r*W_P + j] *= inv;
    }
    __syncthreads();

    // ---- PV: waves split k-chunks of 32; 6 n-tiles of 16 each
    f32x4 o[6];
    #pragma unroll
    for (int nt = 0; nt < 6; ++nt) o[nt] = (f32x4){0.f, 0.f, 0.f, 0.f};
    for (int kc = wave; kc < WSLOT/32; kc += 4) {
        // A-frag from p_s: P[m=lr][k=kc*32+q4*8+e], cvt fp32->bf16
        const float4 pa0 = *reinterpret_cast<const float4*>(p_s + lr*W_P + kc*32 + q4*8);
        const float4 pa1 = *reinterpret_cast<const float4*>(p_s + lr*W_P + kc*32 + q4*8 + 4);
        bf16x8 pa;
        pa[0] = f2bf_bits(pa0.x); pa[1] = f2bf_bits(pa0.y);
        pa[2] = f2bf_bits(pa0.z); pa[3] = f2bf_bits(pa0.w);
        pa[4] = f2bf_bits(pa1.x); pa[5] = f2bf_bits(pa1.y);
        pa[6] = f2bf_bits(pa1.z); pa[7] = f2bf_bits(pa1.w);
        int tc = jlo + kc*32 + q4*8;
        if (tc > T_SEQ-8) tc = T_SEQ-8;          // clamp; p=0 kills junk
        #pragma unroll
        for (int nt = 0; nt < 6; ++nt) {
            const short* vrow = vtb + ((size_t)bh*K_DIM + nt*16 + lr)*T_SEQ + tc;
            const bf16x8 vb = *reinterpret_cast<const bf16x8*>(vrow);
            o[nt] = MFMA16(pa, vb, o[nt], 0, 0, 0);
        }
    }
    // store partial O (C layout: row=q4*4+e, col=nt*16+lr)
    #pragma unroll
    for (int nt = 0; nt < 6; ++nt)
        #pragma unroll
        for (int e = 0; e < 4; ++e)
            po[(wave*IT + q4*4 + e)*PO_S + nt*16 + lr] = o[nt][e];
    __syncthreads();

    // ---- reduce partials + rel_v epilogue + store obtc [b][t][192]
    #pragma unroll
    for (int s = 0; s < 6; ++s) {
        const int idx = tid + s*256;             // 16*96 = 1536 outputs
        const int row = idx / K_DIM, col = idx % K_DIM;
        const int i = i0 + row;
        float v = po[row*PO_S + col] + po[(IT+row)*PO_S + col]
                + po[(2*IT+row)*PO_S + col] + po[(3*IT+row)*PO_S + col];
        #pragma unroll
        for (int dd = 0; dd < 9; ++dd) {
            const int jg = i + dd - 4;
            if (jg >= 0 && jg < T_SEQ)
                v += p_s[row*W_P + (jg - jlo)] * relv[dd*K_DIM + col];
        }
        obtc[((size_t)b*T_SEQ + i)*C_DIM + h*K_DIM + col] = v;
    }
}

// ---------------------------------------------------------------------------
// Kernel 3: output projection -> fp32 y[B,C,T]. 16 t per block.
// ---------------------------------------------------------------------------
__global__ __launch_bounds__(192)
void oproj_kernel(const float* __restrict__ Wo, const float* __restrict__ bo,
                  float* __restrict__ y, const float* __restrict__ obtc)
{
    __shared__ float xs2[16*C_DIM];
    const int b   = blockIdx.x / (T_SEQ/16);
    const int t0  = (blockIdx.x % (T_SEQ/16)) * 16;
    const int tid = threadIdx.x;   // output channel o

    #pragma unroll
    for (int tt = 0; tt < 16; ++tt)
        xs2[tt*C_DIM + tid] = obtc[((size_t)b*T_SEQ + t0 + tt)*C_DIM + tid];
    __syncthreads();

    float acc[16];
    const float bov = bo[tid];
    #pragma unroll
    for (int tt = 0; tt < 16; ++tt) acc[tt] = bov;

    for (int d4 = 0; d4 < C_DIM/4; ++d4) {
        float w[4];
        #pragma unroll
        for (int u = 0; u < 4; ++u) w[u] = Wo[(d4*4 + u)*C_DIM + tid];
        #pragma unroll
        for (int tt = 0; tt < 16; ++tt) {
            const float4 xv = *reinterpret_cast<const float4*>(xs2 + tt*C_DIM + d4*4);
            acc[tt] = fmaf(xv.x, w[0], fmaf(xv.y, w[1], fmaf(xv.z, w[2], fmaf(xv.w, w[3], acc[tt]))));
        }
    }

    float* yp = y + ((size_t)(b*C_DIM + tid))*T_SEQ + t0;
    union { float4 f4[4]; float f[16]; } ou;
    #pragma unroll
    for (int tt = 0; tt < 16; ++tt) ou.f[tt] = acc[tt];
    #pragma unroll
    for (int u = 0; u < 4; ++u)
        *reinterpret_cast<float4*>(yp + 4*u) = ou.f4[u];
}

// ---------------------------------------------------------------------------
extern "C" void kernel_launch(void* const* d_in, const int* in_sizes, int n_in,
                              void* d_out, int out_size, void* d_ws, size_t ws_size,
                              hipStream_t stream)
{
    const float* x    = (const float*)d_in[0];
    const float* c    = (const float*)d_in[1];
    const float* Wq   = (const float*)d_in[2];
    const float* bq   = (const float*)d_in[3];
    const float* Wk   = (const float*)d_in[4];
    const float* bk   = (const float*)d_in[5];
    const float* Wv   = (const float*)d_in[6];
    const float* bv   = (const float*)d_in[7];
    const float* Wo   = (const float*)d_in[8];
    const float* bo   = (const float*)d_in[9];
    const float* relk = (const float*)d_in[10];
    const float* relv = (const float*)d_in[11];
    const int*   mask = (const int*)d_in[12];
    float*       y    = (float*)d_out;

    // ws: qbf | kbf | vtb (bf16, 3.1 MB each) | obtc (fp32, 6.3 MB)
    const size_t NBH = (size_t)B_DIM*H_DIM*T_SEQ*K_DIM;   // 1,572,864
    short* qbf = (short*)d_ws;
    short* kbf = qbf + NBH;
    short* vtb = kbf + NBH;
    float* obtc = (float*)(vtb + NBH);

    hipLaunchKernelGGL(proj_kernel, dim3(B_DIM*(T_SEQ/16)), dim3(192), 0, stream,
                       x, c, Wq, bq, Wk, bk, Wv, bv, qbf, kbf, vtb);
    hipLaunchKernelGGL(attn_kernel, dim3(B_DIM*H_DIM*(T_SEQ/IT)), dim3(256), 0, stream,
                       qbf, kbf, vtb, relk, relv, mask, obtc);
    hipLaunchKernelGGL(oproj_kernel, dim3(B_DIM*(T_SEQ/16)), dim3(192), 0, stream,
                       Wo, bo, y, obtc);
}

// Round 5
// 191.329 us; speedup vs baseline: 2.1441x; 1.4472x over previous
//
#include <hip/hip_runtime.h>
#include <hip/hip_bf16.h>

#define B_DIM 4
#define C_DIM 192
#define T_SEQ 2048
#define H_DIM 2
#define K_DIM 96
#define BAND 256
#define IT 16            // q rows per attn block
#define WSLOT 544        // padded window slots (wlen <= 528), 17 chunks of 32
#define W_P 548          // p_s row stride in dwords (16B aligned, +4 bank skew)
#define PMW 17           // packed-mask words per row

typedef __attribute__((ext_vector_type(8))) short bf16x8;
typedef __attribute__((ext_vector_type(4))) short bf16x4;
typedef __attribute__((ext_vector_type(4))) float f32x4;
#define MFMA16 __builtin_amdgcn_mfma_f32_16x16x32_bf16

__device__ __forceinline__ float bf2f(__hip_bfloat16 v) { return __bfloat162float(v); }
__device__ __forceinline__ float bfbits2f(short s) {
    union { short s; __hip_bfloat16 h; } u; u.s = s; return __bfloat162float(u.h);
}
__device__ __forceinline__ short f2bf_bits(float f) {
    union { __hip_bfloat16 h; short s; } u; u.h = __float2bfloat16(f); return u.s;
}

// ---- workspace layout (bytes) ----
// WqT|WkT|WvT|WoT bf16 [192][192] (WqT prescaled) ; bqs fp32[192] ;
// pm u32[B*T*17] ; qbf,kbf bf16 [bh][t][96] ; vtb bf16 [bh][96][t] ;
// obtc bf16 [b][t][192]
#define OFF_WT(m)  ((size_t)(m)*73728)
#define OFF_BQS    ((size_t)294912)
#define OFF_PM     ((size_t)295680)
#define OFF_QBF    ((size_t)852736)
#define OFF_KBF    (OFF_QBF + 3145728)
#define OFF_VTB    (OFF_KBF + 3145728)
#define OFF_OBTC   (OFF_VTB + 3145728)

// ---------------------------------------------------------------------------
// Prep: transpose W* to bf16 [d][c] (Wq scaled by 1/sqrt(96)); scaled bq.
// ---------------------------------------------------------------------------
__global__ __launch_bounds__(256)
void prep_w_kernel(const float* __restrict__ Wq, const float* __restrict__ Wk,
                   const float* __restrict__ Wv, const float* __restrict__ Wo,
                   const float* __restrict__ bq, char* __restrict__ ws)
{
    const float qscale = 0.10206207261596577f;
    const size_t idx = (size_t)blockIdx.x*256 + threadIdx.x;
    if (blockIdx.x == 576) {               // bias tail
        if (threadIdx.x < C_DIM)
            ((float*)(ws + OFF_BQS))[threadIdx.x] = bq[threadIdx.x]*qscale;
        return;
    }
    const int mi  = (int)(idx / 36864);
    const int rem = (int)(idx % 36864);
    const int d = rem / C_DIM, c = rem % C_DIM;
    const float* src = (mi == 0) ? Wq : (mi == 1) ? Wk : (mi == 2) ? Wv : Wo;
    float v = src[c*C_DIM + d];
    if (mi == 0) v *= qscale;
    ((short*)(ws + OFF_WT(mi)))[d*C_DIM + c] = f2bf_bits(v);
}

// ---------------------------------------------------------------------------
// Prep: pack the band mask into bits. Word w of row (b,i) covers window
// coords [32w,32w+32) with jlo = max(0, (i&~15)-BAND).
// ---------------------------------------------------------------------------
__global__ __launch_bounds__(256)
void pack_mask_kernel(const int* __restrict__ mask, char* __restrict__ ws)
{
    const int idx = blockIdx.x*256 + threadIdx.x;      // B*T*17 = 139264
    const int b = idx / (T_SEQ*PMW);
    const int rem = idx % (T_SEQ*PMW);
    const int i = rem / PMW, w = rem % PMW;
    const int jlo = max(0, (i & ~15) - BAND);
    const int* mrow = mask + ((size_t)b*T_SEQ + i)*T_SEQ;
    unsigned bits = 0;
    #pragma unroll
    for (int g4 = 0; g4 < 8; ++g4) {
        const int jg = jlo + 32*w + 4*g4;
        if (jg + 3 < T_SEQ) {
            const int4 mv = *reinterpret_cast<const int4*>(mrow + jg);
            bits |= (unsigned)(mv.x != 0) << (4*g4);
            bits |= (unsigned)(mv.y != 0) << (4*g4+1);
            bits |= (unsigned)(mv.z != 0) << (4*g4+2);
            bits |= (unsigned)(mv.w != 0) << (4*g4+3);
        } else {
            #pragma unroll
            for (int e = 0; e < 4; ++e)
                if (jg + e < T_SEQ && mrow[jg+e] != 0) bits |= 1u << (4*g4+e);
        }
    }
    ((unsigned*)(ws + OFF_PM))[idx] = bits;
}

// ---------------------------------------------------------------------------
// Kernel 1: q/k/v projection, bf16 MFMA. Block = (b, 16 t), 4 waves.
// q,k: A=xT/cT rows (m=t, LDS), B=W*T rows (n=d, global). v: operands
// swapped (m=d, n=t) so vtb[d][t] stores are contiguous.
// ---------------------------------------------------------------------------
__global__ __launch_bounds__(256)
void proj_kernel(const float* __restrict__ x, const float* __restrict__ cin,
                 const float* __restrict__ bk, const float* __restrict__ bv,
                 char* __restrict__ ws)
{
    __shared__ short xs[IT*C_DIM];   // [t][c] bf16
    __shared__ short cs[IT*C_DIM];
    const int b   = blockIdx.x >> 7;
    const int t0  = (blockIdx.x & 127) * IT;
    const int tid = threadIdx.x;
    const int wave = tid >> 6, lane = tid & 63;
    const int q4 = lane >> 4, lr = lane & 15;

    if (tid < C_DIM) {
        const int c = tid;
        const float* xp = x   + ((size_t)(b*C_DIM + c))*T_SEQ + t0;
        const float* cp = cin + ((size_t)(b*C_DIM + c))*T_SEQ + t0;
        union { float4 f4[4]; float f[16]; } xu, cu;
        #pragma unroll
        for (int u = 0; u < 4; ++u) {
            xu.f4[u] = *reinterpret_cast<const float4*>(xp + 4*u);
            cu.f4[u] = *reinterpret_cast<const float4*>(cp + 4*u);
        }
        #pragma unroll
        for (int tt = 0; tt < IT; ++tt) {
            xs[tt*C_DIM + c] = f2bf_bits(xu.f[tt]);
            cs[tt*C_DIM + c] = f2bf_bits(cu.f[tt]);
        }
    }
    __syncthreads();

    const short* WqT = (const short*)(ws + OFF_WT(0));
    const short* WkT = (const short*)(ws + OFF_WT(1));
    const short* WvT = (const short*)(ws + OFF_WT(2));

    f32x4 qa[3], ka[3], va[3];
    #pragma unroll
    for (int j = 0; j < 3; ++j) {
        qa[j] = (f32x4){0,0,0,0}; ka[j] = (f32x4){0,0,0,0}; va[j] = (f32x4){0,0,0,0};
    }
    for (int kc = 0; kc < 6; ++kc) {
        const int ko = kc*32 + q4*8;
        const bf16x8 xf = *reinterpret_cast<const bf16x8*>(xs + lr*C_DIM + ko);
        const bf16x8 cf = *reinterpret_cast<const bf16x8*>(cs + lr*C_DIM + ko);
        #pragma unroll
        for (int j = 0; j < 3; ++j) {
            const int dt = 3*wave + j;
            const bf16x8 wqf = *reinterpret_cast<const bf16x8*>(WqT + (dt*16 + lr)*C_DIM + ko);
            const bf16x8 wkf = *reinterpret_cast<const bf16x8*>(WkT + (dt*16 + lr)*C_DIM + ko);
            const bf16x8 wvf = *reinterpret_cast<const bf16x8*>(WvT + (dt*16 + lr)*C_DIM + ko);
            qa[j] = MFMA16(xf, wqf, qa[j], 0, 0, 0);   // m=t, n=d
            ka[j] = MFMA16(cf, wkf, ka[j], 0, 0, 0);
            va[j] = MFMA16(wvf, cf, va[j], 0, 0, 0);   // m=d, n=t
        }
    }

    const float* bqs = (const float*)(ws + OFF_BQS);
    short* qbf = (short*)(ws + OFF_QBF);
    short* kbf = (short*)(ws + OFF_KBF);
    short* vtb = (short*)(ws + OFF_VTB);
    #pragma unroll
    for (int j = 0; j < 3; ++j) {
        const int dt = 3*wave + j;
        {   // q,k: col=d=dt*16+lr, row=t=q4*4+e
            const int d = dt*16 + lr, h = d/K_DIM, kk = d%K_DIM;
            const int bh = b*H_DIM + h;
            const float bq_v = bqs[d], bk_v = bk[d];
            #pragma unroll
            for (int e = 0; e < 4; ++e) {
                const int t = t0 + q4*4 + e;
                const size_t off = ((size_t)bh*T_SEQ + t)*K_DIM + kk;
                qbf[off] = f2bf_bits(qa[j][e] + bq_v);
                kbf[off] = f2bf_bits(ka[j][e] + bk_v);
            }
        }
        {   // v: col=t=lr, row=d=dt*16+q4*4+e
            #pragma unroll
            for (int e = 0; e < 4; ++e) {
                const int d = dt*16 + q4*4 + e, h = d/K_DIM, kk = d%K_DIM;
                const int bh = b*H_DIM + h;
                vtb[((size_t)bh*K_DIM + kk)*T_SEQ + t0 + lr] = f2bf_bits(va[j][e] + bv[d]);
            }
        }
    }
}

// ---------------------------------------------------------------------------
// Kernel 2: banded MFMA attention. Block = (b,h,16 rows), 4 waves.
// LDS 38.5 KB -> 4 blocks/CU. Probabilities stored bf16 in-place.
// ---------------------------------------------------------------------------
__global__ __launch_bounds__(256)
void attn_kernel(const float* __restrict__ relk, const float* __restrict__ relv,
                 char* __restrict__ ws)
{
    __shared__ float p_s[IT*W_P];     // 35.1 KB raw scores / bf16 probs
    __shared__ float shbuf[864];      // phase1: lt[0..256]@0, rl[144]@260; phase2: relv

    const short* qbf = (const short*)(ws + OFF_QBF);
    const short* kbf = (const short*)(ws + OFF_KBF);
    const short* vtb = (const short*)(ws + OFF_VTB);
    const unsigned* pm = (const unsigned*)(ws + OFF_PM);
    short* obtc = (short*)(ws + OFF_OBTC);

    const int bh  = blockIdx.x >> 7;
    const int i0  = (blockIdx.x & 127) * IT;
    const int b   = bh / H_DIM;
    const int h   = bh % H_DIM;
    const int tid = threadIdx.x;
    const int wave = tid >> 6, lane = tid & 63;
    const int q4 = lane >> 4, lr = lane & 15;

    const int jlo  = max(0, i0 - BAND);
    const int jhi  = min(T_SEQ - 1, i0 + IT - 1 + BAND);
    const int wlen = jhi - jlo + 1;
    const size_t qkv_base = (size_t)bh * T_SEQ * K_DIM;

    float* lt = shbuf;
    float* rl = shbuf + 260;
    for (int idx = tid; idx < 257; idx += 256) lt[idx] = log1pf((float)idx);
    if (tid < IT*9) {
        const int r = tid/9, dd = tid%9;
        const short* qrow = qbf + qkv_base + (size_t)(i0 + r)*K_DIM;
        float s = 0.f;
        for (int k = 0; k < K_DIM; ++k)
            s += bfbits2f(qrow[k]) * relk[dd*K_DIM + k];
        rl[tid] = s;
    }

    // Q A-frags
    bf16x8 qa[3];
    {
        const short* qrow = qbf + qkv_base + (size_t)(i0 + lr)*K_DIM + q4*8;
        #pragma unroll
        for (int kc = 0; kc < 3; ++kc)
            qa[kc] = *reinterpret_cast<const bf16x8*>(qrow + kc*32);
    }

    // ---- scores
    for (int jt = wave; jt < WSLOT/16; jt += 4) {
        int jr = jlo + jt*16 + lr;
        if (jr > T_SEQ-1) jr = T_SEQ-1;
        const short* krow = kbf + qkv_base + (size_t)jr*K_DIM + q4*8;
        f32x4 s = {0.f,0.f,0.f,0.f};
        #pragma unroll
        for (int kc = 0; kc < 3; ++kc)
            s = MFMA16(qa[kc], *reinterpret_cast<const bf16x8*>(krow + kc*32), s, 0, 0, 0);
        #pragma unroll
        for (int e = 0; e < 4; ++e)
            p_s[(q4*4 + e)*W_P + jt*16 + lr] = s[e];
    }
    __syncthreads();

    // ---- postprocess + softmax (row r by 16 lanes of its own wave)
    {
        const int r = tid >> 4, sj = tid & 15;
        const int i = i0 + r;
        const int pmrow = (b*T_SEQ + i)*PMW;
        float vals[36];
        float m = -INFINITY;
        #pragma unroll
        for (int mm = 0; mm < 9; ++mm) {
            const int j0 = 4*sj + 64*mm;
            float4 pv = make_float4(0.f,0.f,0.f,0.f);
            unsigned mb = 0;
            if (j0 < WSLOT) {
                pv = *reinterpret_cast<const float4*>(p_s + r*W_P + j0);
                mb = pm[pmrow + (j0 >> 5)] >> (j0 & 31);
            }
            const float pe[4] = {pv.x, pv.y, pv.z, pv.w};
            #pragma unroll
            for (int e = 0; e < 4; ++e) {
                const int j = j0 + e;
                float val = -INFINITY;
                if (j0 < WSLOT && j < wlen) {
                    const int jg = jlo + j, dd = jg - i;
                    const int ad = dd < 0 ? -dd : dd;
                    if (ad <= BAND && ((mb >> e) & 1)) {
                        val = pe[e] - lt[ad];
                        if ((unsigned)(dd + 4) <= 8u) val += rl[r*9 + dd + 4];
                    }
                }
                vals[mm*4 + e] = val;
                m = fmaxf(m, val);
            }
        }
        #pragma unroll
        for (int off = 8; off > 0; off >>= 1) m = fmaxf(m, __shfl_xor(m, off, 64));
        if (m == -INFINITY) m = 0.f;
        float ssum = 0.f;
        #pragma unroll
        for (int u = 0; u < 36; ++u) { vals[u] = __expf(vals[u] - m); ssum += vals[u]; }
        #pragma unroll
        for (int off = 8; off > 0; off >>= 1) ssum += __shfl_xor(ssum, off, 64);
        const float inv = ssum > 0.f ? 1.f/ssum : 0.f;
        short* pb = (short*)p_s;
        #pragma unroll
        for (int mm = 0; mm < 9; ++mm) {
            const int j0 = 4*sj + 64*mm;
            if (j0 < WSLOT) {
                bf16x4 w;
                #pragma unroll
                for (int e = 0; e < 4; ++e) w[e] = f2bf_bits(vals[mm*4+e]*inv);
                *reinterpret_cast<bf16x4*>(pb + r*(2*W_P) + j0) = w;
            }
        }
    }
    __syncthreads();

    // ---- relv -> LDS (overwrites lt/rl) + PV (waves split n-tiles 2/2/1/1)
    for (int idx = tid; idx < 9*K_DIM; idx += 256) shbuf[idx] = relv[idx];

    const short* pb = (const short*)p_s;
    f32x4 o0 = {0.f,0.f,0.f,0.f}, o1 = {0.f,0.f,0.f,0.f};
    for (int kc = 0; kc < WSLOT/32; ++kc) {
        const bf16x8 pa = *reinterpret_cast<const bf16x8*>(pb + lr*(2*W_P) + kc*32 + q4*8);
        int tc = jlo + kc*32 + q4*8;
        if (tc > T_SEQ-8) tc = T_SEQ-8;
        const bf16x8 vb0 = *reinterpret_cast<const bf16x8*>(
            vtb + qkv_base + (size_t)(wave*16 + lr)*T_SEQ + tc);
        o0 = MFMA16(pa, vb0, o0, 0, 0, 0);
        if (wave < 2) {
            const bf16x8 vb1 = *reinterpret_cast<const bf16x8*>(
                vtb + qkv_base + (size_t)((wave+4)*16 + lr)*T_SEQ + tc);
            o1 = MFMA16(pa, vb1, o1, 0, 0, 0);
        }
    }
    __syncthreads();   // relv fully loaded

    // ---- epilogue: rel_v contribution + bf16 store to obtc[b][t][192]
    #pragma unroll
    for (int u = 0; u < 2; ++u) {
        if (u == 1 && wave >= 2) break;
        const int nt = (u == 0) ? wave : wave + 4;
        const f32x4 oc = (u == 0) ? o0 : o1;
        const int col = nt*16 + lr;
        #pragma unroll
        for (int e = 0; e < 4; ++e) {
            const int row = q4*4 + e;
            const int i = i0 + row;
            float v = oc[e];
            #pragma unroll
            for (int dd = 0; dd < 9; ++dd) {
                const int jg = i + dd - 4;
                if (jg >= 0 && jg < T_SEQ)
                    v += bfbits2f(pb[row*(2*W_P) + (jg - jlo)]) * shbuf[dd*K_DIM + col];
            }
            obtc[((size_t)b*T_SEQ + i)*C_DIM + h*K_DIM + col] = f2bf_bits(v);
        }
    }
}

// ---------------------------------------------------------------------------
// Kernel 3: output projection, bf16 MFMA, y^T form -> fp32 y[B,C,T].
// A=WoT rows (m=d), B=obtc rows (n=t), both direct from global.
// ---------------------------------------------------------------------------
__global__ __launch_bounds__(256)
void oproj_kernel(const float* __restrict__ bo, float* __restrict__ y,
                  const char* __restrict__ ws)
{
    const int b   = blockIdx.x >> 7;
    const int t0  = (blockIdx.x & 127) * 16;
    const int tid = threadIdx.x;
    const int wave = tid >> 6, lane = tid & 63;
    const int q4 = lane >> 4, lr = lane & 15;

    const short* WoT  = (const short*)(ws + OFF_WT(3));
    const short* obtc = (const short*)(ws + OFF_OBTC);

    f32x4 a[3];
    #pragma unroll
    for (int j = 0; j < 3; ++j) a[j] = (f32x4){0.f,0.f,0.f,0.f};
    for (int kc = 0; kc < 6; ++kc) {
        const int ko = kc*32 + q4*8;
        const bf16x8 bf = *reinterpret_cast<const bf16x8*>(
            obtc + ((size_t)b*T_SEQ + t0 + lr)*C_DIM + ko);
        #pragma unroll
        for (int j = 0; j < 3; ++j) {
            const bf16x8 af = *reinterpret_cast<const bf16x8*>(
                WoT + ((3*wave + j)*16 + lr)*C_DIM + ko);
            a[j] = MFMA16(af, bf, a[j], 0, 0, 0);
        }
    }
    #pragma unroll
    for (int j = 0; j < 3; ++j) {
        #pragma unroll
        for (int e = 0; e < 4; ++e) {
            const int d = (3*wave + j)*16 + q4*4 + e;
            y[((size_t)b*C_DIM + d)*T_SEQ + t0 + lr] = a[j][e] + bo[d];
        }
    }
}

// ---------------------------------------------------------------------------
extern "C" void kernel_launch(void* const* d_in, const int* in_sizes, int n_in,
                              void* d_out, int out_size, void* d_ws, size_t ws_size,
                              hipStream_t stream)
{
    const float* x    = (const float*)d_in[0];
    const float* c    = (const float*)d_in[1];
    const float* Wq   = (const float*)d_in[2];
    const float* bq   = (const float*)d_in[3];
    const float* Wk   = (const float*)d_in[4];
    const float* bk   = (const float*)d_in[5];
    const float* Wv   = (const float*)d_in[6];
    const float* bv   = (const float*)d_in[7];
    const float* Wo   = (const float*)d_in[8];
    const float* bo   = (const float*)d_in[9];
    const float* relk = (const float*)d_in[10];
    const float* relv = (const float*)d_in[11];
    const int*   mask = (const int*)d_in[12];
    float*       y    = (float*)d_out;
    char*        ws   = (char*)d_ws;

    hipLaunchKernelGGL(prep_w_kernel, dim3(577), dim3(256), 0, stream,
                       Wq, Wk, Wv, Wo, bq, ws);
    hipLaunchKernelGGL(pack_mask_kernel, dim3(544), dim3(256), 0, stream, mask, ws);
    hipLaunchKernelGGL(proj_kernel, dim3(B_DIM*(T_SEQ/16)), dim3(256), 0, stream,
                       x, c, bk, bv, ws);
    hipLaunchKernelGGL(attn_kernel, dim3(B_DIM*H_DIM*(T_SEQ/IT)), dim3(256), 0, stream,
                       relk, relv, ws);
    hipLaunchKernelGGL(oproj_kernel, dim3(B_DIM*(T_SEQ/16)), dim3(256), 0, stream,
                       bo, y, ws);
}

// Round 6
// 179.827 us; speedup vs baseline: 2.2812x; 1.0640x over previous
//
#include <hip/hip_runtime.h>
#include <hip/hip_bf16.h>

#define B_DIM 4
#define C_DIM 192
#define T_SEQ 2048
#define H_DIM 2
#define K_DIM 96
#define BAND 256
#define IT 16            // q rows per attn block
#define WSLOT 544        // padded window slots (wlen <= 528), 17 chunks of 32
#define W_P 548          // p_s row stride in dwords (16B aligned, +4 bank skew)
#define PMW 17           // packed-mask words per row

typedef __attribute__((ext_vector_type(8))) short bf16x8;
typedef __attribute__((ext_vector_type(4))) short bf16x4;
typedef __attribute__((ext_vector_type(4))) float f32x4;
#define MFMA16 __builtin_amdgcn_mfma_f32_16x16x32_bf16

__device__ __forceinline__ float bfbits2f(short s) {
    union { short s; __hip_bfloat16 h; } u; u.s = s; return __bfloat162float(u.h);
}
__device__ __forceinline__ short f2bf_bits(float f) {
    union { __hip_bfloat16 h; short s; } u; u.h = __float2bfloat16(f); return u.s;
}

// ---- workspace layout (bytes) ----
// WqT|WkT|WvT|WoT bf16 [192][192] (WqT prescaled); bqs fp32[192];
// relkbf bf16[16][96] (rows 9..15 zero); pm u32[B*T*17];
// qbf,kbf bf16 [bh][t][96]; vtb bf16 [bh][96][t]; obtc bf16 [b][t][192]
#define OFF_WT(m)  ((size_t)(m)*73728)
#define OFF_BQS    ((size_t)294912)
#define OFF_RELKBF ((size_t)295680)
#define OFF_PM     ((size_t)298752)
#define OFF_QBF    ((size_t)855808)
#define OFF_KBF    (OFF_QBF + 3145728)
#define OFF_VTB    (OFF_KBF + 3145728)
#define OFF_OBTC   (OFF_VTB + 3145728)

// ---------------------------------------------------------------------------
// Prep (fused): [0,576) weight transpose (coalesced reads, strided stores);
// [576,1120) mask bit-pack; 1120: scaled bias + padded bf16 rel-k table.
// ---------------------------------------------------------------------------
__global__ __launch_bounds__(256)
void prep_kernel(const float* __restrict__ Wq, const float* __restrict__ Wk,
                 const float* __restrict__ Wv, const float* __restrict__ Wo,
                 const float* __restrict__ bq, const float* __restrict__ relk,
                 const int* __restrict__ mask, char* __restrict__ ws)
{
    const float qscale = 0.10206207261596577f;
    const int bidx = blockIdx.x;
    const int tid  = threadIdx.x;

    if (bidx < 576) {                       // ---- weight transpose
        const size_t idx = (size_t)bidx*256 + tid;
        const int mi  = (int)(idx / 36864);
        const int rem = (int)(idx % 36864);
        const int c = rem / C_DIM, d = rem % C_DIM;   // consecutive tid -> consecutive d
        const float* src = (mi == 0) ? Wq : (mi == 1) ? Wk : (mi == 2) ? Wv : Wo;
        float v = src[c*C_DIM + d];                    // coalesced read
        if (mi == 0) v *= qscale;
        ((short*)(ws + OFF_WT(mi)))[d*C_DIM + c] = f2bf_bits(v);  // strided store (posted)
        return;
    }
    if (bidx < 1120) {                      // ---- mask pack
        const int idx = (bidx - 576)*256 + tid;        // B*T*17 = 139264
        const int b = idx / (T_SEQ*PMW);
        const int rem = idx % (T_SEQ*PMW);
        const int i = rem / PMW, w = rem % PMW;
        const int jlo = max(0, (i & ~15) - BAND);
        const int* mrow = mask + ((size_t)b*T_SEQ + i)*T_SEQ;
        unsigned bits = 0;
        #pragma unroll
        for (int g4 = 0; g4 < 8; ++g4) {
            const int jg = jlo + 32*w + 4*g4;
            if (jg + 3 < T_SEQ) {
                const int4 mv = *reinterpret_cast<const int4*>(mrow + jg);
                bits |= (unsigned)(mv.x != 0) << (4*g4);
                bits |= (unsigned)(mv.y != 0) << (4*g4+1);
                bits |= (unsigned)(mv.z != 0) << (4*g4+2);
                bits |= (unsigned)(mv.w != 0) << (4*g4+3);
            } else {
                #pragma unroll
                for (int e = 0; e < 4; ++e)
                    if (jg + e < T_SEQ && mrow[jg+e] != 0) bits |= 1u << (4*g4+e);
            }
        }
        ((unsigned*)(ws + OFF_PM))[idx] = bits;
        return;
    }
    // ---- bias + rel-k table
    if (tid < C_DIM)
        ((float*)(ws + OFF_BQS))[tid] = bq[tid]*qscale;
    short* rkb = (short*)(ws + OFF_RELKBF);
    for (int idx = tid; idx < 16*K_DIM; idx += 256) {
        const int row = idx / K_DIM;
        rkb[idx] = (row < 9) ? f2bf_bits(relk[idx]) : (short)0;
    }
}

// ---------------------------------------------------------------------------
// Kernel 1: q/k/v projection, bf16 MFMA. Block = (b, 16 t), 4 waves.
// ---------------------------------------------------------------------------
__global__ __launch_bounds__(256)
void proj_kernel(const float* __restrict__ x, const float* __restrict__ cin,
                 const float* __restrict__ bk, const float* __restrict__ bv,
                 char* __restrict__ ws)
{
    __shared__ short xs[IT*C_DIM];   // [t][c] bf16
    __shared__ short cs[IT*C_DIM];
    const int b   = blockIdx.x >> 7;
    const int t0  = (blockIdx.x & 127) * IT;
    const int tid = threadIdx.x;
    const int wave = tid >> 6, lane = tid & 63;
    const int q4 = lane >> 4, lr = lane & 15;

    // staging: 768 float4 chunks (192 rows x 4), all 256 threads, 64B/4-lane groups
    for (int l = tid; l < 768; l += 256) {
        const int cr = l >> 2, u = l & 3;
        const size_t off = (size_t)(b*C_DIM + cr)*T_SEQ + t0 + 4*u;
        const float4 xv = *reinterpret_cast<const float4*>(x + off);
        const float4 cv = *reinterpret_cast<const float4*>(cin + off);
        xs[(4*u+0)*C_DIM + cr] = f2bf_bits(xv.x);
        xs[(4*u+1)*C_DIM + cr] = f2bf_bits(xv.y);
        xs[(4*u+2)*C_DIM + cr] = f2bf_bits(xv.z);
        xs[(4*u+3)*C_DIM + cr] = f2bf_bits(xv.w);
        cs[(4*u+0)*C_DIM + cr] = f2bf_bits(cv.x);
        cs[(4*u+1)*C_DIM + cr] = f2bf_bits(cv.y);
        cs[(4*u+2)*C_DIM + cr] = f2bf_bits(cv.z);
        cs[(4*u+3)*C_DIM + cr] = f2bf_bits(cv.w);
    }
    __syncthreads();

    const short* WqT = (const short*)(ws + OFF_WT(0));
    const short* WkT = (const short*)(ws + OFF_WT(1));
    const short* WvT = (const short*)(ws + OFF_WT(2));

    f32x4 qa[3], ka[3], va[3];
    #pragma unroll
    for (int j = 0; j < 3; ++j) {
        qa[j] = (f32x4){0,0,0,0}; ka[j] = (f32x4){0,0,0,0}; va[j] = (f32x4){0,0,0,0};
    }
    for (int kc = 0; kc < 6; ++kc) {
        const int ko = kc*32 + q4*8;
        const bf16x8 xf = *reinterpret_cast<const bf16x8*>(xs + lr*C_DIM + ko);
        const bf16x8 cf = *reinterpret_cast<const bf16x8*>(cs + lr*C_DIM + ko);
        #pragma unroll
        for (int j = 0; j < 3; ++j) {
            const int dt = 3*wave + j;
            const bf16x8 wqf = *reinterpret_cast<const bf16x8*>(WqT + (dt*16 + lr)*C_DIM + ko);
            const bf16x8 wkf = *reinterpret_cast<const bf16x8*>(WkT + (dt*16 + lr)*C_DIM + ko);
            const bf16x8 wvf = *reinterpret_cast<const bf16x8*>(WvT + (dt*16 + lr)*C_DIM + ko);
            qa[j] = MFMA16(xf, wqf, qa[j], 0, 0, 0);   // m=t, n=d
            ka[j] = MFMA16(cf, wkf, ka[j], 0, 0, 0);
            va[j] = MFMA16(wvf, cf, va[j], 0, 0, 0);   // m=d, n=t
        }
    }

    const float* bqs = (const float*)(ws + OFF_BQS);
    short* qbf = (short*)(ws + OFF_QBF);
    short* kbf = (short*)(ws + OFF_KBF);
    short* vtb = (short*)(ws + OFF_VTB);
    #pragma unroll
    for (int j = 0; j < 3; ++j) {
        const int dt = 3*wave + j;
        {   // q,k: col=d=dt*16+lr, row=t=q4*4+e
            const int d = dt*16 + lr, h = d/K_DIM, kk = d%K_DIM;
            const int bh = b*H_DIM + h;
            const float bq_v = bqs[d], bk_v = bk[d];
            #pragma unroll
            for (int e = 0; e < 4; ++e) {
                const int t = t0 + q4*4 + e;
                const size_t off = ((size_t)bh*T_SEQ + t)*K_DIM + kk;
                qbf[off] = f2bf_bits(qa[j][e] + bq_v);
                kbf[off] = f2bf_bits(ka[j][e] + bk_v);
            }
        }
        {   // v: col=t=lr, row=d=dt*16+q4*4+e
            #pragma unroll
            for (int e = 0; e < 4; ++e) {
                const int d = dt*16 + q4*4 + e, h = d/K_DIM, kk = d%K_DIM;
                const int bh = b*H_DIM + h;
                vtb[((size_t)bh*K_DIM + kk)*T_SEQ + t0 + lr] = f2bf_bits(va[j][e] + bv[d]);
            }
        }
    }
}

// ---------------------------------------------------------------------------
// Kernel 2: banded MFMA attention. Block = (b,h,16 rows), 4 waves.
// rel-k logits computed by wave 3 as one extra MFMA tile (no scalar chain).
// ---------------------------------------------------------------------------
__global__ __launch_bounds__(256)
void attn_kernel(const float* __restrict__ relv, char* __restrict__ ws)
{
    __shared__ float p_s[IT*W_P];     // 35.1 KB raw scores / bf16 probs
    __shared__ float shbuf[864];      // phase1: lt[0..256]@0, rl[144]@260; phase2: relv

    const short* qbf = (const short*)(ws + OFF_QBF);
    const short* kbf = (const short*)(ws + OFF_KBF);
    const short* vtb = (const short*)(ws + OFF_VTB);
    const short* rkb = (const short*)(ws + OFF_RELKBF);
    const unsigned* pm = (const unsigned*)(ws + OFF_PM);
    short* obtc = (short*)(ws + OFF_OBTC);

    const int bh  = blockIdx.x >> 7;
    const int i0  = (blockIdx.x & 127) * IT;
    const int b   = bh / H_DIM;
    const int h   = bh % H_DIM;
    const int tid = threadIdx.x;
    const int wave = tid >> 6, lane = tid & 63;
    const int q4 = lane >> 4, lr = lane & 15;

    const int jlo  = max(0, i0 - BAND);
    const int jhi  = min(T_SEQ - 1, i0 + IT - 1 + BAND);
    const int wlen = jhi - jlo + 1;
    const size_t qkv_base = (size_t)bh * T_SEQ * K_DIM;

    float* lt = shbuf;
    float* rl = shbuf + 260;
    for (int idx = tid; idx < 257; idx += 256) lt[idx] = log1pf((float)idx);

    // Q A-frags
    bf16x8 qa[3];
    {
        const short* qrow = qbf + qkv_base + (size_t)(i0 + lr)*K_DIM + q4*8;
        #pragma unroll
        for (int kc = 0; kc < 3; ++kc)
            qa[kc] = *reinterpret_cast<const bf16x8*>(qrow + kc*32);
    }

    // ---- scores (waves interleave j-tiles); wave 3 also does the rel-k tile
    for (int jt = wave; jt < WSLOT/16; jt += 4) {
        int jr = jlo + jt*16 + lr;
        if (jr > T_SEQ-1) jr = T_SEQ-1;
        const short* krow = kbf + qkv_base + (size_t)jr*K_DIM + q4*8;
        f32x4 s = {0.f,0.f,0.f,0.f};
        #pragma unroll
        for (int kc = 0; kc < 3; ++kc)
            s = MFMA16(qa[kc], *reinterpret_cast<const bf16x8*>(krow + kc*32), s, 0, 0, 0);
        #pragma unroll
        for (int e = 0; e < 4; ++e)
            p_s[(q4*4 + e)*W_P + jt*16 + lr] = s[e];
    }
    if (wave == 3) {                  // rl[r][dd] = q_r · relk_dd via MFMA
        const short* krow = rkb + lr*K_DIM + q4*8;
        f32x4 s = {0.f,0.f,0.f,0.f};
        #pragma unroll
        for (int kc = 0; kc < 3; ++kc)
            s = MFMA16(qa[kc], *reinterpret_cast<const bf16x8*>(krow + kc*32), s, 0, 0, 0);
        if (lr < 9) {
            #pragma unroll
            for (int e = 0; e < 4; ++e)
                rl[(q4*4 + e)*9 + lr] = s[e];
        }
    }
    __syncthreads();

    // ---- postprocess + softmax (row r by 16 lanes of its own wave)
    {
        const int r = tid >> 4, sj = tid & 15;
        const int i = i0 + r;
        const int pmrow = (b*T_SEQ + i)*PMW;
        float vals[36];
        float m = -INFINITY;
        #pragma unroll
        for (int mm = 0; mm < 9; ++mm) {
            const int j0 = 4*sj + 64*mm;
            float4 pv = make_float4(0.f,0.f,0.f,0.f);
            unsigned mb = 0;
            if (j0 < WSLOT) {
                pv = *reinterpret_cast<const float4*>(p_s + r*W_P + j0);
                mb = pm[pmrow + (j0 >> 5)] >> (j0 & 31);
            }
            const float pe[4] = {pv.x, pv.y, pv.z, pv.w};
            #pragma unroll
            for (int e = 0; e < 4; ++e) {
                const int j = j0 + e;
                float val = -INFINITY;
                if (j0 < WSLOT && j < wlen) {
                    const int jg = jlo + j, dd = jg - i;
                    const int ad = dd < 0 ? -dd : dd;
                    if (ad <= BAND && ((mb >> e) & 1)) {
                        val = pe[e] - lt[ad];
                        if ((unsigned)(dd + 4) <= 8u) val += rl[r*9 + dd + 4];
                    }
                }
                vals[mm*4 + e] = val;
                m = fmaxf(m, val);
            }
        }
        #pragma unroll
        for (int off = 8; off > 0; off >>= 1) m = fmaxf(m, __shfl_xor(m, off, 64));
        if (m == -INFINITY) m = 0.f;
        float ssum = 0.f;
        #pragma unroll
        for (int u = 0; u < 36; ++u) { vals[u] = __expf(vals[u] - m); ssum += vals[u]; }
        #pragma unroll
        for (int off = 8; off > 0; off >>= 1) ssum += __shfl_xor(ssum, off, 64);
        const float inv = ssum > 0.f ? 1.f/ssum : 0.f;
        short* pb = (short*)p_s;
        #pragma unroll
        for (int mm = 0; mm < 9; ++mm) {
            const int j0 = 4*sj + 64*mm;
            if (j0 < WSLOT) {
                bf16x4 w;
                #pragma unroll
                for (int e = 0; e < 4; ++e) w[e] = f2bf_bits(vals[mm*4+e]*inv);
                *reinterpret_cast<bf16x4*>(pb + r*(2*W_P) + j0) = w;
            }
        }
    }
    __syncthreads();

    // ---- relv -> LDS (overwrites lt/rl) + PV (waves split n-tiles 2/2/1/1)
    for (int idx = tid; idx < 9*K_DIM; idx += 256) shbuf[idx] = relv[idx];

    const short* pb = (const short*)p_s;
    f32x4 o0 = {0.f,0.f,0.f,0.f}, o1 = {0.f,0.f,0.f,0.f};
    for (int kc = 0; kc < WSLOT/32; ++kc) {
        const bf16x8 pa = *reinterpret_cast<const bf16x8*>(pb + lr*(2*W_P) + kc*32 + q4*8);
        int tc = jlo + kc*32 + q4*8;
        if (tc > T_SEQ-8) tc = T_SEQ-8;
        const bf16x8 vb0 = *reinterpret_cast<const bf16x8*>(
            vtb + qkv_base + (size_t)(wave*16 + lr)*T_SEQ + tc);
        o0 = MFMA16(pa, vb0, o0, 0, 0, 0);
        if (wave < 2) {
            const bf16x8 vb1 = *reinterpret_cast<const bf16x8*>(
                vtb + qkv_base + (size_t)((wave+4)*16 + lr)*T_SEQ + tc);
            o1 = MFMA16(pa, vb1, o1, 0, 0, 0);
        }
    }
    __syncthreads();   // relv fully loaded

    // ---- epilogue: rel_v contribution + bf16 store to obtc[b][t][192]
    #pragma unroll
    for (int u = 0; u < 2; ++u) {
        if (u == 1 && wave >= 2) break;
        const int nt = (u == 0) ? wave : wave + 4;
        const f32x4 oc = (u == 0) ? o0 : o1;
        const int col = nt*16 + lr;
        #pragma unroll
        for (int e = 0; e < 4; ++e) {
            const int row = q4*4 + e;
            const int i = i0 + row;
            float v = oc[e];
            #pragma unroll
            for (int dd = 0; dd < 9; ++dd) {
                const int jg = i + dd - 4;
                if (jg >= 0 && jg < T_SEQ)
                    v += bfbits2f(pb[row*(2*W_P) + (jg - jlo)]) * shbuf[dd*K_DIM + col];
            }
            obtc[((size_t)b*T_SEQ + i)*C_DIM + h*K_DIM + col] = f2bf_bits(v);
        }
    }
}

// ---------------------------------------------------------------------------
// Kernel 3: output projection, bf16 MFMA, y^T form -> fp32 y[B,C,T].
// ---------------------------------------------------------------------------
__global__ __launch_bounds__(256)
void oproj_kernel(const float* __restrict__ bo, float* __restrict__ y,
                  const char* __restrict__ ws)
{
    const int b   = blockIdx.x >> 7;
    const int t0  = (blockIdx.x & 127) * 16;
    const int tid = threadIdx.x;
    const int wave = tid >> 6, lane = tid & 63;
    const int q4 = lane >> 4, lr = lane & 15;

    const short* WoT  = (const short*)(ws + OFF_WT(3));
    const short* obtc = (const short*)(ws + OFF_OBTC);

    f32x4 a[3];
    #pragma unroll
    for (int j = 0; j < 3; ++j) a[j] = (f32x4){0.f,0.f,0.f,0.f};
    for (int kc = 0; kc < 6; ++kc) {
        const int ko = kc*32 + q4*8;
        const bf16x8 bf = *reinterpret_cast<const bf16x8*>(
            obtc + ((size_t)b*T_SEQ + t0 + lr)*C_DIM + ko);
        #pragma unroll
        for (int j = 0; j < 3; ++j) {
            const bf16x8 af = *reinterpret_cast<const bf16x8*>(
                WoT + ((3*wave + j)*16 + lr)*C_DIM + ko);
            a[j] = MFMA16(af, bf, a[j], 0, 0, 0);
        }
    }
    #pragma unroll
    for (int j = 0; j < 3; ++j) {
        #pragma unroll
        for (int e = 0; e < 4; ++e) {
            const int d = (3*wave + j)*16 + q4*4 + e;
            y[((size_t)b*C_DIM + d)*T_SEQ + t0 + lr] = a[j][e] + bo[d];
        }
    }
}

// ---------------------------------------------------------------------------
extern "C" void kernel_launch(void* const* d_in, const int* in_sizes, int n_in,
                              void* d_out, int out_size, void* d_ws, size_t ws_size,
                              hipStream_t stream)
{
    const float* x    = (const float*)d_in[0];
    const float* c    = (const float*)d_in[1];
    const float* Wq   = (const float*)d_in[2];
    const float* bq   = (const float*)d_in[3];
    const float* Wk   = (const float*)d_in[4];
    const float* bk   = (const float*)d_in[5];
    const float* Wv   = (const float*)d_in[6];
    const float* bv   = (const float*)d_in[7];
    const float* Wo   = (const float*)d_in[8];
    const float* bo   = (const float*)d_in[9];
    const float* relk = (const float*)d_in[10];
    const float* relv = (const float*)d_in[11];
    const int*   mask = (const int*)d_in[12];
    float*       y    = (float*)d_out;
    char*        ws   = (char*)d_ws;

    hipLaunchKernelGGL(prep_kernel, dim3(1121), dim3(256), 0, stream,
                       Wq, Wk, Wv, Wo, bq, relk, mask, ws);
    hipLaunchKernelGGL(proj_kernel, dim3(B_DIM*(T_SEQ/16)), dim3(256), 0, stream,
                       x, c, bk, bv, ws);
    hipLaunchKernelGGL(attn_kernel, dim3(B_DIM*H_DIM*(T_SEQ/IT)), dim3(256), 0, stream,
                       relv, ws);
    hipLaunchKernelGGL(oproj_kernel, dim3(B_DIM*(T_SEQ/16)), dim3(256), 0, stream,
                       bo, y, ws);
}